// Round 1
// baseline (30.574 us; speedup 1.0000x reference)
//
#include <hip/hip_runtime.h>
#include <math.h>

#define ALPHA 0.2f

// Problem constants (shape-specialized per harness): B=4, N=512, IN=128, OUT=64.
//
// Derivation (see analysis): the reference's cat(axis=1)+reshape scrambles rows so
//  i < 256 : e[b,i,j] = lrelu(g[b, 2i + (j>=256)]),  g = h·(a1+a2)
//  i >= 256: e[b,i,j] = lrelu(p[b,2(j%256)] + q[b,2(j%256)+1]),  indep. of i
// which collapses softmax+PV to per-batch reductions.

// ws layout (floats):
//  h  : [0,      131072)   (4*512*64)
//  p  : [131072, 133120)
//  q  : [133120, 135168)
//  g  : [135168, 137216)
//  S0 : [137216, 137472)   (4*64)
//  S1 : [137472, 137728)
//  R2 : [137728, 137984)   row value for all i>=256 (pre-ELU)

__global__ __launch_bounds__(256) void k1_gemm_pqg(
    const float* __restrict__ X, const float* __restrict__ W,
    const float* __restrict__ a, float* __restrict__ h,
    float* __restrict__ p, float* __restrict__ q, float* __restrict__ g)
{
    __shared__ float Ws[128 * 64];               // 32 KB staged W
    const float4* W4 = (const float4*)W;
    float4* Ws4 = (float4*)Ws;
    for (int idx = threadIdx.x; idx < 128 * 64 / 4; idx += 256)
        Ws4[idx] = W4[idx];
    __syncthreads();

    const int row  = blockIdx.x * 4 + (threadIdx.x >> 6);  // 0..2047 = b*512+r
    const int lane = threadIdx.x & 63;
    const float4* xrow = (const float4*)(X + row * 128);

    float acc = 0.f;
#pragma unroll
    for (int k4 = 0; k4 < 32; ++k4) {
        float4 x4 = xrow[k4];
        acc = fmaf(x4.x, Ws[(k4 * 4 + 0) * 64 + lane], acc);
        acc = fmaf(x4.y, Ws[(k4 * 4 + 1) * 64 + lane], acc);
        acc = fmaf(x4.z, Ws[(k4 * 4 + 2) * 64 + lane], acc);
        acc = fmaf(x4.w, Ws[(k4 * 4 + 3) * 64 + lane], acc);
    }
    h[row * 64 + lane] = acc;

    float pv = acc * a[lane];        // dot(h_row, a1) partial
    float qv = acc * a[64 + lane];   // dot(h_row, a2) partial
#pragma unroll
    for (int off = 32; off >= 1; off >>= 1) {
        pv += __shfl_xor(pv, off);
        qv += __shfl_xor(qv, off);
    }
    if (lane == 0) {
        p[row] = pv;
        q[row] = qv;
        g[row] = pv + qv;
    }
}

__global__ __launch_bounds__(256) void k2_batch_reduce(
    const float* __restrict__ h, const float* __restrict__ p,
    const float* __restrict__ q, float* __restrict__ S0,
    float* __restrict__ S1, float* __restrict__ R2)
{
    const int b = blockIdx.x;
    const int t = threadIdx.x;          // 0..255
    const int c = t & 63, grp = t >> 6; // col, row-group

    __shared__ float red[256];
    __shared__ float ec_s[256];

    // c[t] = lrelu(p[b,2t] + q[b,2t+1]), t = jj in [0,256)
    float cc = p[b * 512 + 2 * t] + q[b * 512 + 2 * t + 1];
    cc = cc > 0.f ? cc : ALPHA * cc;

    // max over 256
    red[t] = cc;
    __syncthreads();
    for (int s = 128; s > 0; s >>= 1) {
        if (t < s) red[t] = fmaxf(red[t], red[t + s]);
        __syncthreads();
    }
    const float mc = red[0];
    __syncthreads();

    const float ec = expf(cc - mc);
    ec_s[t] = ec;
    red[t] = ec;
    __syncthreads();
    for (int s = 128; s > 0; s >>= 1) {
        if (t < s) red[t] += red[t + s];
        __syncthreads();
    }
    const float Z = red[0];
    __syncthreads();

    // column sums S0,S1 and weighted sum T over jj
    float s0 = 0.f, s1 = 0.f, tt = 0.f;
    const float* hb = h + b * 512 * 64;
    for (int j = grp; j < 256; j += 4) {
        float h0 = hb[j * 64 + c];
        float h1 = hb[(j + 256) * 64 + c];
        s0 += h0;
        s1 += h1;
        tt = fmaf(ec_s[j], h0 + h1, tt);
    }

    red[t] = s0; __syncthreads();
    if (grp == 0) S0[b * 64 + c] = red[c] + red[64 + c] + red[128 + c] + red[192 + c];
    __syncthreads();
    red[t] = s1; __syncthreads();
    if (grp == 0) S1[b * 64 + c] = red[c] + red[64 + c] + red[128 + c] + red[192 + c];
    __syncthreads();
    red[t] = tt; __syncthreads();
    if (grp == 0)
        R2[b * 64 + c] = (red[c] + red[64 + c] + red[128 + c] + red[192 + c]) / (2.f * Z);
}

__global__ __launch_bounds__(256) void k3_finalize(
    const float* __restrict__ g, const float* __restrict__ S0,
    const float* __restrict__ S1, const float* __restrict__ R2,
    float* __restrict__ out)
{
    const int row = blockIdx.x * 4 + (threadIdx.x >> 6);  // 0..2047
    const int c   = threadIdx.x & 63;
    const int b   = row >> 9;
    const int i   = row & 511;

    float hp;
    if (i < 256) {
        float u = g[b * 512 + 2 * i];
        float v = g[b * 512 + 2 * i + 1];
        u = u > 0.f ? u : ALPHA * u;
        v = v > 0.f ? v : ALPHA * v;
        const float m  = fmaxf(u, v);
        const float w0 = expf(u - m), w1 = expf(v - m);
        hp = (w0 * S0[b * 64 + c] + w1 * S1[b * 64 + c]) / (256.f * (w0 + w1));
    } else {
        hp = R2[b * 64 + c];
    }
    out[row * 64 + c] = hp > 0.f ? hp : expm1f(hp);  // ELU(alpha=1)
}

extern "C" void kernel_launch(void* const* d_in, const int* in_sizes, int n_in,
                              void* d_out, int out_size, void* d_ws, size_t ws_size,
                              hipStream_t stream) {
    const float* X = (const float*)d_in[0];   // (4,512,128)
    // d_in[1] = adj — dead code in the reference (mask overwritten by softmax)
    const float* W = (const float*)d_in[2];   // (128,64)
    const float* a = (const float*)d_in[3];   // (128,1)
    float* out = (float*)d_out;               // (4,512,64)

    float* ws = (float*)d_ws;
    float* h  = ws;
    float* p  = ws + 131072;
    float* q  = ws + 133120;
    float* g  = ws + 135168;
    float* S0 = ws + 137216;
    float* S1 = ws + 137472;
    float* R2 = ws + 137728;

    hipLaunchKernelGGL(k1_gemm_pqg, dim3(512), dim3(256), 0, stream, X, W, a, h, p, q, g);
    hipLaunchKernelGGL(k2_batch_reduce, dim3(4), dim3(256), 0, stream, h, p, q, S0, S1, R2);
    hipLaunchKernelGGL(k3_finalize, dim3(512), dim3(256), 0, stream, g, S0, S1, R2, out);
}